// Round 6
// baseline (364.712 us; speedup 1.0000x reference)
//
#include <hip/hip_runtime.h>
#include <math.h>

#define HH 384
#define WW 640
#define HWSZ (HH*WW)
#define BB 2
#define NN 6
#define BPG 256                 // blocks per group in phaseA
#define PACKB (12*HWSZ/256)     // 11520
#define REFB  (2*HWSZ/256)      // 1920

// ws float-offset layout:
//  header (zeroed by memset each call):
//   WS_P 0..143, WS_INVK 144..161, WS_CAM 176..182,
//   WS_ACC 192..287 (12 groups x 8), WS_CNT 296, WS_RSUM 304..307 (b*2 + {sum,sumsq}),
//   WS_STAT 320..391 (12 x 6)
//  CACHE_OFF: 12*HWSZ uint  (unorm10 RGB + 2b wm sample cache)   11.8 MB
//  RP_OFF   : 2*HWSZ float4 (rs3, depth, rmask, 0)                7.9 MB
//  PK_OFF   : 12*HWSZ uint  (unorm10 RGB + 2b mask src texels)   11.8 MB
#define WS_P      0
#define WS_INVK   144
#define WS_CAM    176
#define WS_ACC    192
#define WS_CNT    296
#define WS_RSUM   304
#define WS_STAT   320
#define CACHE_OFF 512
#define RP_OFF    (CACHE_OFF + 12 * HWSZ)
#define PK_OFF    (RP_OFF + 8 * HWSZ)
#define WS_NEED   (PK_OFF + 12 * HWSZ)

__device__ __forceinline__ unsigned enc10(float c) {
    c = fminf(fmaxf(c, 0.0f), 1.0f);
    return (unsigned)rintf(c * 1023.0f);
}
__device__ __forceinline__ unsigned encTex(float r, float g, float b, float m) {
    unsigned mb = (unsigned)rintf(fminf(fmaxf(m, 0.0f), 1.0f) * 3.0f);
    return enc10(r) | (enc10(g) << 10) | (enc10(b) << 20) | (mb << 30);
}
__device__ __forceinline__ void decTex(unsigned u, float& r, float& g, float& b, float& m) {
    const float s = 1.0f / 1023.0f;
    r = (float)(u & 1023u) * s;
    g = (float)((u >> 10) & 1023u) * s;
    b = (float)((u >> 20) & 1023u) * s;
    m = (float)(u >> 30) * (1.0f / 3.0f);
}

__device__ __forceinline__ void get_cams(const void* camI, const void* nbr,
                                         int& ci, int& n0, int& n1) {
    ci = ((const int*)camI)[0];
    long long a = ((const long long*)nbr)[0];
    long long bq = ((const long long*)nbr)[1];
    if (a >= 0 && a < NN && bq >= 0 && bq < NN) { n0 = (int)a; n1 = (int)bq; }
    else { n0 = ((const int*)nbr)[0]; n1 = ((const int*)nbr)[1]; }
}
__device__ __forceinline__ int cam_of_w(int w, int ci, int n0, int n1) {
    if (w < 2) return ci;
    return (w == 2 || w == 4) ? n0 : n1;
}

// ---- projection, f32 op-order mirrored to the JAX reference, no FMA contraction ----
__device__ __forceinline__ void project_pix(const float* __restrict__ Pm, const float* __restrict__ ik,
                                            float fx, float fy, float d,
                                            float& gx, float& gy, float& sx, float& sy)
{
    float q0 = __fadd_rn(__fadd_rn(__fmul_rn(ik[0], fx), __fmul_rn(ik[1], fy)), ik[2]);
    float q1 = __fadd_rn(__fadd_rn(__fmul_rn(ik[3], fx), __fmul_rn(ik[4], fy)), ik[5]);
    float q2 = __fadd_rn(__fadd_rn(__fmul_rn(ik[6], fx), __fmul_rn(ik[7], fy)), ik[8]);
    float a0 = __fmul_rn(q0, d), a1 = __fmul_rn(q1, d), a2 = __fmul_rn(q2, d);
    float p0 = __fadd_rn(__fadd_rn(__fadd_rn(__fmul_rn(Pm[0], a0), __fmul_rn(Pm[1], a1)), __fmul_rn(Pm[2], a2)), Pm[3]);
    float p1 = __fadd_rn(__fadd_rn(__fadd_rn(__fmul_rn(Pm[4], a0), __fmul_rn(Pm[5], a1)), __fmul_rn(Pm[6], a2)), Pm[7]);
    float p2 = __fadd_rn(__fadd_rn(__fadd_rn(__fmul_rn(Pm[8], a0), __fmul_rn(Pm[9], a1)), __fmul_rn(Pm[10], a2)), Pm[11]);
    float z  = __fadd_rn(p2, 1e-7f);
    float xx = __fdiv_rn(p0, z);
    float yy = __fdiv_rn(p1, z);
    gx = __fmul_rn(__fsub_rn(__fdiv_rn(xx, 639.0f), 0.5f), 2.0f);
    gy = __fmul_rn(__fsub_rn(__fdiv_rn(yy, 383.0f), 0.5f), 2.0f);
    sx = __fmul_rn(__fmul_rn(__fadd_rn(gx, 1.0f), 0.5f), 639.0f);
    sy = __fmul_rn(__fmul_rn(__fadd_rn(gy, 1.0f), 0.5f), 383.0f);
}

// 4 predicated 4B scattered loads; nearest mask from a corner texel.
__device__ __forceinline__ void sample_u10(const unsigned* __restrict__ pk,
                                           const float* Pm, const float* ik, float d, int px_i, int py_i,
                                           float& i0, float& i1, float& i2, float& wmv, bool& isnanv)
{
    float gx, gy, sx, sy;
    project_pix(Pm, ik, (float)px_i, (float)py_i, d, gx, gy, sx, sy);
    float x0f = floorf(sx), y0f = floorf(sy);
    float wx = __fsub_rn(sx, x0f), wy = __fsub_rn(sy, y0f);
    int x0 = (int)x0f, y0 = (int)y0f;
    int x1 = x0 + 1, y1 = y0 + 1;
    bool vx0 = (x0 >= 0) && (x0 < WW), vx1 = (x1 >= 0) && (x1 < WW);
    bool vy0 = (y0 >= 0) && (y0 < HH), vy1 = (y1 >= 0) && (y1 < HH);
    unsigned u00 = 0u, u01 = 0u, u10 = 0u, u11 = 0u;
    if (vy0 && vx0) u00 = pk[y0 * WW + x0];
    if (vy0 && vx1) u01 = pk[y0 * WW + x1];
    if (vy1 && vx0) u10 = pk[y1 * WW + x0];
    if (vy1 && vx1) u11 = pk[y1 * WW + x1];
    float w00 = (1.0f - wx) * (1.0f - wy);
    float w01 = wx * (1.0f - wy);
    float w10 = (1.0f - wx) * wy;
    float w11 = wx * wy;
    float r00,g00,b00,m00, r01,g01,b01,m01, r10,g10,b10,m10, r11,g11,b11,m11;
    decTex(u00, r00,g00,b00,m00); decTex(u01, r01,g01,b01,m01);
    decTex(u10, r10,g10,b10,m10); decTex(u11, r11,g11,b11,m11);
    float v0 = ((r00*w00 + r01*w01) + r10*w10) + r11*w11;
    float v1 = ((g00*w00 + g01*w01) + g10*w10) + g11*w11;
    float v2 = ((b00*w00 + b01*w01) + b10*w10) + b11*w11;
    isnanv = (v0 != v0);
    i0 = isnanv ? 2.0f : v0;
    i1 = (v1 != v1) ? 2.0f : v1;
    i2 = (v2 != v2) ? 2.0f : v2;
    bool invalid = (gx > 1.0f) || (gx < -1.0f) || (gy > 1.0f) || (gy < -1.0f);
    float xr = rintf(sx), yr = rintf(sy);
    int xi = (int)xr, yi = (int)yr;
    bool vm = (xi >= 0) && (xi < WW) && (yi >= 0) && (yi < HH) && !invalid;
    bool selx = (xi == x1), sely = (yi == y1);
    float msel = sely ? (selx ? m11 : m10) : (selx ? m01 : m00);
    wmv = vm ? msel : 0.0f;
}

// Merged prep: pack 12 src images (unorm10), pack ref-side float4 + ref sums, setup matrices.
__global__ __launch_bounds__(256) void vr_prep(
    const float* __restrict__ prev, const float* __restrict__ nxt,
    const float* __restrict__ org, const float* __restrict__ maskT,
    const float* __restrict__ depthT,
    const float* __restrict__ K, const float* __restrict__ invK,
    const float* __restrict__ p2c, const float* __restrict__ c2n,
    const float* __restrict__ rel, const void* __restrict__ camI,
    const void* __restrict__ nbr, float* __restrict__ ws)
{
    int ci, n0, n1;
    get_cams(camI, nbr, ci, n0, n1);
    int blk = blockIdx.x;
    if (blk < PACKB) {
        int gid = blk * 256 + threadIdx.x;
        int group = gid / HWSZ;
        int p = gid - group * HWSZ;
        int w = group / BB, b = group % BB;
        int cam = cam_of_w(w, ci, n0, n1);
        const float* simg  = ((w == 0 || w == 2 || w == 3) ? prev : nxt) + (size_t)(b * NN + cam) * 3 * HWSZ;
        float m = maskT[(size_t)(b * NN + cam) * HWSZ + p];
        unsigned u = encTex(simg[p], simg[HWSZ + p], simg[2 * HWSZ + p], m);
        ((unsigned*)(ws + PK_OFF))[(size_t)group * HWSZ + p] = u;
    } else if (blk < PACKB + REFB) {
        int gid = (blk - PACKB) * 256 + threadIdx.x;
        int b = gid / HWSZ;
        int p = gid - b * HWSZ;
        const float* rimg = org + (size_t)(b * NN + ci) * 3 * HWSZ;
        float r0 = rimg[p], r1 = rimg[HWSZ + p], r2 = rimg[2 * HWSZ + p];
        float rm = maskT[(size_t)(b * NN + ci) * HWSZ + p];
        float d  = depthT[(size_t)(b * NN + ci) * HWSZ + p];
        float rs3 = r0 + r1 + r2;
        float rsq = r0 * r0 + r1 * r1 + r2 * r2;
        float4 v; v.x = rs3; v.y = d; v.z = rm; v.w = 0.0f;
        ((float4*)(ws + RP_OFF))[(size_t)b * HWSZ + p] = v;
        // block-reduce ref sums (once per batch, instead of 6x in phaseA)
        __shared__ float sred[4][2];
        int lane = threadIdx.x & 63, wv = threadIdx.x >> 6;
        float a = rs3, q = rsq;
        for (int off = 32; off; off >>= 1) { a += __shfl_down(a, off); q += __shfl_down(q, off); }
        if (lane == 0) { sred[wv][0] = a; sred[wv][1] = q; }
        __syncthreads();
        if (threadIdx.x == 0) {
            atomicAdd(&ws[WS_RSUM + b * 2 + 0], sred[0][0] + sred[1][0] + sred[2][0] + sred[3][0]);
            atomicAdd(&ws[WS_RSUM + b * 2 + 1], sred[0][1] + sred[1][1] + sred[2][1] + sred[3][1]);
        }
    } else if (threadIdx.x == 0) {
        int* cams = (int*)(ws + WS_CAM);
        cams[0] = ci; cams[1] = ci; cams[2] = n0; cams[3] = n1; cams[4] = n0; cams[5] = n1;
        cams[6] = ci;
        for (int b = 0; b < BB; b++) {
            const float* ik = invK + (size_t)(b * NN + ci) * 16;
            float* dst = ws + WS_INVK + b * 9;
            dst[0] = ik[0]; dst[1] = ik[1]; dst[2] = ik[2];
            dst[3] = ik[4]; dst[4] = ik[5]; dst[5] = ik[6];
            dst[6] = ik[8]; dst[7] = ik[9]; dst[8] = ik[10];
            for (int w = 0; w < 6; w++) {
                int cam = cam_of_w(w, ci, n0, n1);
                const float* Km = K + (size_t)(b * NN + cam) * 16;
                const float* T;
                if (w == 0)      T = p2c + (size_t)(b * NN + ci) * 16;
                else if (w == 1) T = c2n + (size_t)(b * NN + ci) * 16;
                else {
                    int f = (w >= 4) ? 1 : 0;
                    int n = (w == 3 || w == 5) ? 1 : 0;
                    T = rel + (size_t)((f * 2 + n) * BB + b) * 16;
                }
                float* Pd = ws + WS_P + (w * BB + b) * 12;
                for (int i = 0; i < 3; i++)
                    for (int j = 0; j < 4; j++) {
                        float s = __fadd_rn(__fadd_rn(__fadd_rn(
                                      __fmul_rn(Km[i * 4 + 0], T[0 * 4 + j]),
                                      __fmul_rn(Km[i * 4 + 1], T[1 * 4 + j])),
                                      __fmul_rn(Km[i * 4 + 2], T[2 * 4 + j])),
                                      __fmul_rn(Km[i * 4 + 3], T[3 * 4 + j]));
                        Pd[i * 4 + j] = s;
                    }
            }
        }
    }
}

__device__ __forceinline__ float ws_atomic_read(float* p) { return atomicAdd(p, 0.0f); }

__global__ __launch_bounds__(256) void vr_phaseA(float* __restrict__ ws)
{
    int group = blockIdx.x % 12;        // round-robin: all groups progress together
    int blkin = blockIdx.x / 12;
    int b = group % BB;
    float Pl[12], ikl[9];
    {
        const float* Pm = ws + WS_P + group * 12;
        const float* ik = ws + WS_INVK + b * 9;
#pragma unroll
        for (int i = 0; i < 12; i++) Pl[i] = Pm[i];
#pragma unroll
        for (int i = 0; i < 9; i++) ikl[i] = ik[i];
    }
    const float4* rpk = (const float4*)(ws + RP_OFF) + (size_t)b * HWSZ;
    const unsigned* pk = (const unsigned*)(ws + PK_OFF) + (size_t)group * HWSZ;
    unsigned* cache = (unsigned*)(ws + CACHE_OFF) + (size_t)group * HWSZ;

    float acc[5] = {0, 0, 0, 0, 0};
    for (int p = blkin * 256 + threadIdx.x; p < HWSZ; p += BPG * 256) {
        int py_i = p / WW, px_i = p - py_i * WW;
        float4 rp = rpk[p];
        float rs3 = rp.x, d = rp.y, rm = rp.z;
        float i0, i1, i2, wmv; bool isnanv;
        sample_u10(pk, Pl, ikl, d, px_i, py_i, i0, i1, i2, wmv, isnanv);
        cache[p] = isnanv ? (2u << 30) : encTex(i0, i1, i2, wmv);
        float m = (rm * wmv > 0.0f) ? 1.0f : 0.0f;
        float ws3 = i0 + i1 + i2;
        acc[0] += m;
        acc[1] += rs3 * m;
        acc[2] += ws3 * m;
        acc[3] += ws3;
        acc[4] += i0 * i0 + i1 * i1 + i2 * i2;
    }
    __shared__ float sred[4][5];
    int lane = threadIdx.x & 63, wv = threadIdx.x >> 6;
#pragma unroll
    for (int k = 0; k < 5; k++) {
        float v2 = acc[k];
        for (int off = 32; off; off >>= 1) v2 += __shfl_down(v2, off);
        if (lane == 0) sred[wv][k] = v2;
    }
    __syncthreads();
    if (threadIdx.x < 5) {
        float s = sred[0][threadIdx.x] + sred[1][threadIdx.x] + sred[2][threadIdx.x] + sred[3][threadIdx.x];
        atomicAdd(&ws[WS_ACC + group * 8 + threadIdx.x], s);
    }
    // last-block finalize
    __threadfence();
    __shared__ int slast;
    if (threadIdx.x == 0) {
        unsigned old = atomicAdd((unsigned*)(ws + WS_CNT), 1u);
        slast = (old == (unsigned)(gridDim.x - 1)) ? 1 : 0;
    }
    __syncthreads();
    if (slast && threadIdx.x < 12) {
        int t = threadIdx.x;
        int wb = t % BB;
        float* ac = ws + WS_ACC + t * 8;
        double cnt  = ws_atomic_read(&ac[0]);
        double smsk = ws_atomic_read(&ac[1]);
        double wmsk = ws_atomic_read(&ac[2]);
        double wsum = ws_atomic_read(&ac[3]);
        double wsq  = ws_atomic_read(&ac[4]);
        double ssum = ws_atomic_read(&ws[WS_RSUM + wb * 2 + 0]);
        double ssq  = ws_atomic_read(&ws[WS_RSUM + wb * 2 + 1]);
        int w = t / BB;
        double c0 = ws_atomic_read(&ws[WS_ACC + (w * BB + 0) * 8]);
        double c1 = ws_atomic_read(&ws[WS_ACC + (w * BB + 1) * 8]);
        double msum = 3.0 * cnt;
        double NT = 3.0 * (double)HWSZ;
        double smean = smsk / (msum + 1e-8);
        double svar  = (ssq - 2.0 * smean * ssum + NT * smean * smean) / NT;
        double sstd  = sqrt(svar + 1e-16);
        double wmean = wmsk / (msum + 1e-8);
        double wvar  = (wsq - 2.0 * wmean * wsum + NT * wmean * wmean) / NT;
        double wstd  = sqrt(wvar + 1e-16);
        float az = (c0 == 0.0 || c1 == 0.0) ? 1.0f : 0.0f;
        float* st = ws + WS_STAT + t * 6;
        st[0] = (float)smean; st[1] = (float)sstd;
        st[2] = (float)wmean; st[3] = (float)wstd;
        st[4] = az;
    }
}

__global__ __launch_bounds__(256) void vr_phaseB(const float* __restrict__ ws, float* __restrict__ out)
{
    int idx = blockIdx.x * 256 + threadIdx.x;
    int ob = idx / (BB * HWSZ);
    int rem = idx - ob * (BB * HWSZ);
    int b = rem / HWSZ;
    int p = rem - b * HWSZ;
    int w0 = (ob == 0) ? 0 : (ob == 1) ? 1 : (ob == 2) ? 2 : 4;
    int nw = (ob < 2) ? 1 : 2;
    float o0 = 0, o1 = 0, o2 = 0, om = 0;
    for (int k = 0; k < nw; k++) {
        int w = w0 + k;
        int group = w * BB + b;
        unsigned u = ((const unsigned*)(ws + CACHE_OFF))[(size_t)group * HWSZ + p];
        float i0, i1, i2, wmv;
        unsigned mb = u >> 30;
        if (mb == 2u) { i0 = i1 = i2 = 2.0f; wmv = 0.0f; }
        else decTex(u, i0, i1, i2, wmv);
        const float* st = ws + WS_STAT + group * 6;
        float smean = st[0], sstd = st[1], wmean = st[2], wstd = st[3];
        bool az = st[4] != 0.0f;
        float v0, v1, v2;
        if (az) { v0 = i0; v1 = i1; v2 = i2; }
        else {
            v0 = ((i0 - wmean) / (wstd + 1e-8f)) * sstd + smean; v0 *= wmv;
            v1 = ((i1 - wmean) / (wstd + 1e-8f)) * sstd + smean; v1 *= wmv;
            v2 = ((i2 - wmean) / (wstd + 1e-8f)) * sstd + smean; v2 *= wmv;
        }
        o0 += v0; o1 += v1; o2 += v2; om += wmv;
    }
    float* base = out + ((size_t)b * 16 + ob * 4) * HWSZ;
    base[p] = o0;
    base[HWSZ + p] = o1;
    base[2 * HWSZ + p] = o2;
    base[3 * HWSZ + p] = om;
}

extern "C" void kernel_launch(void* const* d_in, const int* in_sizes, int n_in,
                              void* d_out, int out_size, void* d_ws, size_t ws_size,
                              hipStream_t stream)
{
    const float* prev  = (const float*)d_in[0];
    const float* org   = (const float*)d_in[1];
    const float* nxt   = (const float*)d_in[2];
    const float* maskT = (const float*)d_in[3];
    const float* K     = (const float*)d_in[4];
    const float* invK  = (const float*)d_in[5];
    const float* dep   = (const float*)d_in[6];
    const float* p2c   = (const float*)d_in[7];
    const float* c2n   = (const float*)d_in[8];
    const float* rel   = (const float*)d_in[9];
    const void*  camI  = d_in[10];
    const void*  nbr   = d_in[11];
    float* ws  = (float*)d_ws;
    float* out = (float*)d_out;

    // header zero (acc, counter, rsum, stats). ws_size known >= 78 MB from R4/R5; WS_NEED = 43.3 MB.
    hipMemsetAsync(ws, 0, 2048, stream);
    hipLaunchKernelGGL(vr_prep, dim3(PACKB + REFB + 1), dim3(256), 0, stream,
                       prev, nxt, org, maskT, dep, K, invK, p2c, c2n, rel, camI, nbr, ws);
    hipLaunchKernelGGL(vr_phaseA, dim3(12 * BPG), dim3(256), 0, stream, ws);
    hipLaunchKernelGGL(vr_phaseB, dim3(4 * BB * HWSZ / 256), dim3(256), 0, stream, ws, out);
}

// Round 7
// 105.226 us; speedup vs baseline: 3.4660x; 3.4660x over previous
//
#include <hip/hip_runtime.h>
#include <math.h>

#define HH 384
#define WW 640
#define HWSZ (HH*WW)
#define BB 2
#define NN 6
#define BPG 256                 // blocks per group in phaseA
#define PACKB (12*HWSZ/256)     // 11520
#define REFB  (2*HWSZ/256)      // 1920

// ws float-offset layout:
//  header (zeroed by memset each call):
//   WS_P 0..143, WS_INVK 144..161, WS_CAM 176..182,
//   WS_ACC 192..287 (12 groups x 8), WS_RSUM 304..307 (b*2 + {sum,sumsq}),
//   WS_STAT 320..391 (12 x 6)
//  CACHE_OFF: 12*HWSZ uint  (unorm10 RGB + 2b wm sample cache)   11.8 MB
//  RP_OFF   : 2*HWSZ float4 (rs3, depth, rmask, 0)                7.9 MB
//  PK_OFF   : 12*HWSZ uint  (unorm10 RGB + 2b mask src texels)   11.8 MB
#define WS_P      0
#define WS_INVK   144
#define WS_CAM    176
#define WS_ACC    192
#define WS_RSUM   304
#define WS_STAT   320
#define CACHE_OFF 512
#define RP_OFF    (CACHE_OFF + 12 * HWSZ)
#define PK_OFF    (RP_OFF + 8 * HWSZ)
#define WS_NEED   (PK_OFF + 12 * HWSZ)

__device__ __forceinline__ unsigned enc10(float c) {
    c = fminf(fmaxf(c, 0.0f), 1.0f);
    return (unsigned)rintf(c * 1023.0f);
}
__device__ __forceinline__ unsigned encTex(float r, float g, float b, float m) {
    unsigned mb = (unsigned)rintf(fminf(fmaxf(m, 0.0f), 1.0f) * 3.0f);
    return enc10(r) | (enc10(g) << 10) | (enc10(b) << 20) | (mb << 30);
}
__device__ __forceinline__ void decTex(unsigned u, float& r, float& g, float& b, float& m) {
    const float s = 1.0f / 1023.0f;
    r = (float)(u & 1023u) * s;
    g = (float)((u >> 10) & 1023u) * s;
    b = (float)((u >> 20) & 1023u) * s;
    m = (float)(u >> 30) * (1.0f / 3.0f);
}

__device__ __forceinline__ void get_cams(const void* camI, const void* nbr,
                                         int& ci, int& n0, int& n1) {
    ci = ((const int*)camI)[0];
    long long a = ((const long long*)nbr)[0];
    long long bq = ((const long long*)nbr)[1];
    if (a >= 0 && a < NN && bq >= 0 && bq < NN) { n0 = (int)a; n1 = (int)bq; }
    else { n0 = ((const int*)nbr)[0]; n1 = ((const int*)nbr)[1]; }
}
__device__ __forceinline__ int cam_of_w(int w, int ci, int n0, int n1) {
    if (w < 2) return ci;
    return (w == 2 || w == 4) ? n0 : n1;
}

// ---- projection, f32 op-order mirrored to the JAX reference, no FMA contraction ----
__device__ __forceinline__ void project_pix(const float* __restrict__ Pm, const float* __restrict__ ik,
                                            float fx, float fy, float d,
                                            float& gx, float& gy, float& sx, float& sy)
{
    float q0 = __fadd_rn(__fadd_rn(__fmul_rn(ik[0], fx), __fmul_rn(ik[1], fy)), ik[2]);
    float q1 = __fadd_rn(__fadd_rn(__fmul_rn(ik[3], fx), __fmul_rn(ik[4], fy)), ik[5]);
    float q2 = __fadd_rn(__fadd_rn(__fmul_rn(ik[6], fx), __fmul_rn(ik[7], fy)), ik[8]);
    float a0 = __fmul_rn(q0, d), a1 = __fmul_rn(q1, d), a2 = __fmul_rn(q2, d);
    float p0 = __fadd_rn(__fadd_rn(__fadd_rn(__fmul_rn(Pm[0], a0), __fmul_rn(Pm[1], a1)), __fmul_rn(Pm[2], a2)), Pm[3]);
    float p1 = __fadd_rn(__fadd_rn(__fadd_rn(__fmul_rn(Pm[4], a0), __fmul_rn(Pm[5], a1)), __fmul_rn(Pm[6], a2)), Pm[7]);
    float p2 = __fadd_rn(__fadd_rn(__fadd_rn(__fmul_rn(Pm[8], a0), __fmul_rn(Pm[9], a1)), __fmul_rn(Pm[10], a2)), Pm[11]);
    float z  = __fadd_rn(p2, 1e-7f);
    float xx = __fdiv_rn(p0, z);
    float yy = __fdiv_rn(p1, z);
    gx = __fmul_rn(__fsub_rn(__fdiv_rn(xx, 639.0f), 0.5f), 2.0f);
    gy = __fmul_rn(__fsub_rn(__fdiv_rn(yy, 383.0f), 0.5f), 2.0f);
    sx = __fmul_rn(__fmul_rn(__fadd_rn(gx, 1.0f), 0.5f), 639.0f);
    sy = __fmul_rn(__fmul_rn(__fadd_rn(gy, 1.0f), 0.5f), 383.0f);
}

// 4 predicated 4B scattered loads; nearest mask from a corner texel.
__device__ __forceinline__ void sample_u10(const unsigned* __restrict__ pk,
                                           const float* Pm, const float* ik, float d, int px_i, int py_i,
                                           float& i0, float& i1, float& i2, float& wmv, bool& isnanv)
{
    float gx, gy, sx, sy;
    project_pix(Pm, ik, (float)px_i, (float)py_i, d, gx, gy, sx, sy);
    float x0f = floorf(sx), y0f = floorf(sy);
    float wx = __fsub_rn(sx, x0f), wy = __fsub_rn(sy, y0f);
    int x0 = (int)x0f, y0 = (int)y0f;
    int x1 = x0 + 1, y1 = y0 + 1;
    bool vx0 = (x0 >= 0) && (x0 < WW), vx1 = (x1 >= 0) && (x1 < WW);
    bool vy0 = (y0 >= 0) && (y0 < HH), vy1 = (y1 >= 0) && (y1 < HH);
    unsigned u00 = 0u, u01 = 0u, u10 = 0u, u11 = 0u;
    if (vy0 && vx0) u00 = pk[y0 * WW + x0];
    if (vy0 && vx1) u01 = pk[y0 * WW + x1];
    if (vy1 && vx0) u10 = pk[y1 * WW + x0];
    if (vy1 && vx1) u11 = pk[y1 * WW + x1];
    float w00 = (1.0f - wx) * (1.0f - wy);
    float w01 = wx * (1.0f - wy);
    float w10 = (1.0f - wx) * wy;
    float w11 = wx * wy;
    float r00,g00,b00,m00, r01,g01,b01,m01, r10,g10,b10,m10, r11,g11,b11,m11;
    decTex(u00, r00,g00,b00,m00); decTex(u01, r01,g01,b01,m01);
    decTex(u10, r10,g10,b10,m10); decTex(u11, r11,g11,b11,m11);
    float v0 = ((r00*w00 + r01*w01) + r10*w10) + r11*w11;
    float v1 = ((g00*w00 + g01*w01) + g10*w10) + g11*w11;
    float v2 = ((b00*w00 + b01*w01) + b10*w10) + b11*w11;
    isnanv = (v0 != v0);
    i0 = isnanv ? 2.0f : v0;
    i1 = (v1 != v1) ? 2.0f : v1;
    i2 = (v2 != v2) ? 2.0f : v2;
    bool invalid = (gx > 1.0f) || (gx < -1.0f) || (gy > 1.0f) || (gy < -1.0f);
    float xr = rintf(sx), yr = rintf(sy);
    int xi = (int)xr, yi = (int)yr;
    bool vm = (xi >= 0) && (xi < WW) && (yi >= 0) && (yi < HH) && !invalid;
    bool selx = (xi == x1), sely = (yi == y1);
    float msel = sely ? (selx ? m11 : m10) : (selx ? m01 : m00);
    wmv = vm ? msel : 0.0f;
}

// Merged prep: pack 12 src images (unorm10), pack ref-side float4 + ref sums, setup matrices.
__global__ __launch_bounds__(256) void vr_prep(
    const float* __restrict__ prev, const float* __restrict__ nxt,
    const float* __restrict__ org, const float* __restrict__ maskT,
    const float* __restrict__ depthT,
    const float* __restrict__ K, const float* __restrict__ invK,
    const float* __restrict__ p2c, const float* __restrict__ c2n,
    const float* __restrict__ rel, const void* __restrict__ camI,
    const void* __restrict__ nbr, float* __restrict__ ws)
{
    int ci, n0, n1;
    get_cams(camI, nbr, ci, n0, n1);
    int blk = blockIdx.x;
    if (blk < PACKB) {
        int gid = blk * 256 + threadIdx.x;
        int group = gid / HWSZ;
        int p = gid - group * HWSZ;
        int w = group / BB, b = group % BB;
        int cam = cam_of_w(w, ci, n0, n1);
        const float* simg  = ((w == 0 || w == 2 || w == 3) ? prev : nxt) + (size_t)(b * NN + cam) * 3 * HWSZ;
        float m = maskT[(size_t)(b * NN + cam) * HWSZ + p];
        unsigned u = encTex(simg[p], simg[HWSZ + p], simg[2 * HWSZ + p], m);
        ((unsigned*)(ws + PK_OFF))[(size_t)group * HWSZ + p] = u;
    } else if (blk < PACKB + REFB) {
        int gid = (blk - PACKB) * 256 + threadIdx.x;
        int b = gid / HWSZ;
        int p = gid - b * HWSZ;
        const float* rimg = org + (size_t)(b * NN + ci) * 3 * HWSZ;
        float r0 = rimg[p], r1 = rimg[HWSZ + p], r2 = rimg[2 * HWSZ + p];
        float rm = maskT[(size_t)(b * NN + ci) * HWSZ + p];
        float d  = depthT[(size_t)(b * NN + ci) * HWSZ + p];
        float rs3 = r0 + r1 + r2;
        float rsq = r0 * r0 + r1 * r1 + r2 * r2;
        float4 v; v.x = rs3; v.y = d; v.z = rm; v.w = 0.0f;
        ((float4*)(ws + RP_OFF))[(size_t)b * HWSZ + p] = v;
        // block-reduce ref sums (once per batch, instead of 6x in phaseA)
        __shared__ float sred[4][2];
        int lane = threadIdx.x & 63, wv = threadIdx.x >> 6;
        float a = rs3, q = rsq;
        for (int off = 32; off; off >>= 1) { a += __shfl_down(a, off); q += __shfl_down(q, off); }
        if (lane == 0) { sred[wv][0] = a; sred[wv][1] = q; }
        __syncthreads();
        if (threadIdx.x == 0) {
            atomicAdd(&ws[WS_RSUM + b * 2 + 0], sred[0][0] + sred[1][0] + sred[2][0] + sred[3][0]);
            atomicAdd(&ws[WS_RSUM + b * 2 + 1], sred[0][1] + sred[1][1] + sred[2][1] + sred[3][1]);
        }
    } else if (threadIdx.x == 0) {
        int* cams = (int*)(ws + WS_CAM);
        cams[0] = ci; cams[1] = ci; cams[2] = n0; cams[3] = n1; cams[4] = n0; cams[5] = n1;
        cams[6] = ci;
        for (int b = 0; b < BB; b++) {
            const float* ik = invK + (size_t)(b * NN + ci) * 16;
            float* dst = ws + WS_INVK + b * 9;
            dst[0] = ik[0]; dst[1] = ik[1]; dst[2] = ik[2];
            dst[3] = ik[4]; dst[4] = ik[5]; dst[5] = ik[6];
            dst[6] = ik[8]; dst[7] = ik[9]; dst[8] = ik[10];
            for (int w = 0; w < 6; w++) {
                int cam = cam_of_w(w, ci, n0, n1);
                const float* Km = K + (size_t)(b * NN + cam) * 16;
                const float* T;
                if (w == 0)      T = p2c + (size_t)(b * NN + ci) * 16;
                else if (w == 1) T = c2n + (size_t)(b * NN + ci) * 16;
                else {
                    int f = (w >= 4) ? 1 : 0;
                    int n = (w == 3 || w == 5) ? 1 : 0;
                    T = rel + (size_t)((f * 2 + n) * BB + b) * 16;
                }
                float* Pd = ws + WS_P + (w * BB + b) * 12;
                for (int i = 0; i < 3; i++)
                    for (int j = 0; j < 4; j++) {
                        float s = __fadd_rn(__fadd_rn(__fadd_rn(
                                      __fmul_rn(Km[i * 4 + 0], T[0 * 4 + j]),
                                      __fmul_rn(Km[i * 4 + 1], T[1 * 4 + j])),
                                      __fmul_rn(Km[i * 4 + 2], T[2 * 4 + j])),
                                      __fmul_rn(Km[i * 4 + 3], T[3 * 4 + j]));
                        Pd[i * 4 + j] = s;
                    }
            }
        }
    }
}

__global__ __launch_bounds__(256) void vr_phaseA(float* __restrict__ ws)
{
    int group = blockIdx.x % 12;        // round-robin: all groups progress together
    int blkin = blockIdx.x / 12;
    int b = group % BB;
    float Pl[12], ikl[9];
    {
        const float* Pm = ws + WS_P + group * 12;
        const float* ik = ws + WS_INVK + b * 9;
#pragma unroll
        for (int i = 0; i < 12; i++) Pl[i] = Pm[i];
#pragma unroll
        for (int i = 0; i < 9; i++) ikl[i] = ik[i];
    }
    const float4* rpk = (const float4*)(ws + RP_OFF) + (size_t)b * HWSZ;
    const unsigned* pk = (const unsigned*)(ws + PK_OFF) + (size_t)group * HWSZ;
    unsigned* cache = (unsigned*)(ws + CACHE_OFF) + (size_t)group * HWSZ;

    float acc[5] = {0, 0, 0, 0, 0};
    for (int p = blkin * 256 + threadIdx.x; p < HWSZ; p += BPG * 256) {
        int py_i = p / WW, px_i = p - py_i * WW;
        float4 rp = rpk[p];
        float rs3 = rp.x, d = rp.y, rm = rp.z;
        float i0, i1, i2, wmv; bool isnanv;
        sample_u10(pk, Pl, ikl, d, px_i, py_i, i0, i1, i2, wmv, isnanv);
        cache[p] = isnanv ? (2u << 30) : encTex(i0, i1, i2, wmv);
        float m = (rm * wmv > 0.0f) ? 1.0f : 0.0f;
        float ws3 = i0 + i1 + i2;
        acc[0] += m;
        acc[1] += rs3 * m;
        acc[2] += ws3 * m;
        acc[3] += ws3;
        acc[4] += i0 * i0 + i1 * i1 + i2 * i2;
    }
    __shared__ float sred[4][5];
    int lane = threadIdx.x & 63, wv = threadIdx.x >> 6;
#pragma unroll
    for (int k = 0; k < 5; k++) {
        float v2 = acc[k];
        for (int off = 32; off; off >>= 1) v2 += __shfl_down(v2, off);
        if (lane == 0) sred[wv][k] = v2;
    }
    __syncthreads();
    if (threadIdx.x < 5) {
        float s = sred[0][threadIdx.x] + sred[1][threadIdx.x] + sred[2][threadIdx.x] + sred[3][threadIdx.x];
        atomicAdd(&ws[WS_ACC + group * 8 + threadIdx.x], s);
    }
}

__global__ void vr_finalize(float* __restrict__ ws)
{
    int t = threadIdx.x;
    if (t >= 12) return;
    int w = t / BB;
    int wb = t % BB;
    const float* ac = ws + WS_ACC + t * 8;
    double cnt  = ac[0], smsk = ac[1], wmsk = ac[2];
    double wsum = ac[3], wsq  = ac[4];
    double ssum = ws[WS_RSUM + wb * 2 + 0];
    double ssq  = ws[WS_RSUM + wb * 2 + 1];
    double msum = 3.0 * cnt;
    double NT = 3.0 * (double)HWSZ;
    double smean = smsk / (msum + 1e-8);
    double svar  = (ssq - 2.0 * smean * ssum + NT * smean * smean) / NT;
    double sstd  = sqrt(svar + 1e-16);
    double wmean = wmsk / (msum + 1e-8);
    double wvar  = (wsq - 2.0 * wmean * wsum + NT * wmean * wmean) / NT;
    double wstd  = sqrt(wvar + 1e-16);
    float c0 = ws[WS_ACC + (w * BB + 0) * 8];
    float c1 = ws[WS_ACC + (w * BB + 1) * 8];
    float az = (c0 == 0.0f || c1 == 0.0f) ? 1.0f : 0.0f;
    float* st = ws + WS_STAT + t * 6;
    st[0] = (float)smean; st[1] = (float)sstd;
    st[2] = (float)wmean; st[3] = (float)wstd;
    st[4] = az;
}

__global__ __launch_bounds__(256) void vr_phaseB(const float* __restrict__ ws, float* __restrict__ out)
{
    int idx = blockIdx.x * 256 + threadIdx.x;
    int ob = idx / (BB * HWSZ);
    int rem = idx - ob * (BB * HWSZ);
    int b = rem / HWSZ;
    int p = rem - b * HWSZ;
    int w0 = (ob == 0) ? 0 : (ob == 1) ? 1 : (ob == 2) ? 2 : 4;
    int nw = (ob < 2) ? 1 : 2;
    float o0 = 0, o1 = 0, o2 = 0, om = 0;
    for (int k = 0; k < nw; k++) {
        int w = w0 + k;
        int group = w * BB + b;
        unsigned u = ((const unsigned*)(ws + CACHE_OFF))[(size_t)group * HWSZ + p];
        float i0, i1, i2, wmv;
        unsigned mb = u >> 30;
        if (mb == 2u) { i0 = i1 = i2 = 2.0f; wmv = 0.0f; }
        else decTex(u, i0, i1, i2, wmv);
        const float* st = ws + WS_STAT + group * 6;
        float smean = st[0], sstd = st[1], wmean = st[2], wstd = st[3];
        bool az = st[4] != 0.0f;
        float v0, v1, v2;
        if (az) { v0 = i0; v1 = i1; v2 = i2; }
        else {
            v0 = ((i0 - wmean) / (wstd + 1e-8f)) * sstd + smean; v0 *= wmv;
            v1 = ((i1 - wmean) / (wstd + 1e-8f)) * sstd + smean; v1 *= wmv;
            v2 = ((i2 - wmean) / (wstd + 1e-8f)) * sstd + smean; v2 *= wmv;
        }
        o0 += v0; o1 += v1; o2 += v2; om += wmv;
    }
    float* base = out + ((size_t)b * 16 + ob * 4) * HWSZ;
    base[p] = o0;
    base[HWSZ + p] = o1;
    base[2 * HWSZ + p] = o2;
    base[3 * HWSZ + p] = om;
}

extern "C" void kernel_launch(void* const* d_in, const int* in_sizes, int n_in,
                              void* d_out, int out_size, void* d_ws, size_t ws_size,
                              hipStream_t stream)
{
    const float* prev  = (const float*)d_in[0];
    const float* org   = (const float*)d_in[1];
    const float* nxt   = (const float*)d_in[2];
    const float* maskT = (const float*)d_in[3];
    const float* K     = (const float*)d_in[4];
    const float* invK  = (const float*)d_in[5];
    const float* dep   = (const float*)d_in[6];
    const float* p2c   = (const float*)d_in[7];
    const float* c2n   = (const float*)d_in[8];
    const float* rel   = (const float*)d_in[9];
    const void*  camI  = d_in[10];
    const void*  nbr   = d_in[11];
    float* ws  = (float*)d_ws;
    float* out = (float*)d_out;

    // header zero (acc, rsum, stats). ws_size known >= 78 MB from R4/R5; WS_NEED = 43.3 MB.
    hipMemsetAsync(ws, 0, 2048, stream);
    hipLaunchKernelGGL(vr_prep, dim3(PACKB + REFB + 1), dim3(256), 0, stream,
                       prev, nxt, org, maskT, dep, K, invK, p2c, c2n, rel, camI, nbr, ws);
    hipLaunchKernelGGL(vr_phaseA, dim3(12 * BPG), dim3(256), 0, stream, ws);
    hipLaunchKernelGGL(vr_finalize, dim3(1), dim3(64), 0, stream, ws);
    hipLaunchKernelGGL(vr_phaseB, dim3(4 * BB * HWSZ / 256), dim3(256), 0, stream, ws, out);
}

// Round 8
// 64.897 us; speedup vs baseline: 5.6198x; 1.6214x over previous
//
#include <hip/hip_runtime.h>
#include <math.h>

#define HH 384
#define WW 640
#define HWSZ (HH*WW)
#define BB 2
#define NN 6
#define BPG 256                 // blocks per group in phaseA
#define GPB 240                 // blocks per image in pack/packref (HWSZ/1024)

// ws float-offset layout:
//  header (memset 2048B each call): WS_P 0..143, WS_INVK 144..161, WS_CAM 176..182,
//   WS_ACC 192..287 (12 x 8), WS_STAT 320..391 (12 x 6)
//  CACHE_OFF: 12*HWSZ uint  (unorm10 RGB + 2b wm sample cache)   11.8 MB
//  RP_OFF   : 2*HWSZ float4 (rs3, depth, rmask, 0)                7.9 MB
//  PK_OFF   : 12*HWSZ uint  (unorm10 RGB + 2b mask src texels)   11.8 MB
//  PART_OFF : 480 float2 ref partial sums (no atomics)
#define WS_P      0
#define WS_INVK   144
#define WS_CAM    176
#define WS_ACC    192
#define WS_STAT   320
#define CACHE_OFF 512
#define RP_OFF    (CACHE_OFF + 12 * HWSZ)
#define PK_OFF    (RP_OFF + 8 * HWSZ)
#define PART_OFF  (PK_OFF + 12 * HWSZ)

__device__ __forceinline__ unsigned enc10(float c) {
    c = fminf(fmaxf(c, 0.0f), 1.0f);
    return (unsigned)rintf(c * 1023.0f);
}
__device__ __forceinline__ unsigned encTex(float r, float g, float b, float m) {
    unsigned mb = (unsigned)rintf(fminf(fmaxf(m, 0.0f), 1.0f) * 3.0f);
    return enc10(r) | (enc10(g) << 10) | (enc10(b) << 20) | (mb << 30);
}
__device__ __forceinline__ void decTex(unsigned u, float& r, float& g, float& b, float& m) {
    const float s = 1.0f / 1023.0f;
    r = (float)(u & 1023u) * s;
    g = (float)((u >> 10) & 1023u) * s;
    b = (float)((u >> 20) & 1023u) * s;
    m = (float)(u >> 30) * (1.0f / 3.0f);
}

__device__ __forceinline__ void get_cams(const void* camI, const void* nbr,
                                         int& ci, int& n0, int& n1) {
    ci = ((const int*)camI)[0];
    long long a = ((const long long*)nbr)[0];
    long long bq = ((const long long*)nbr)[1];
    if (a >= 0 && a < NN && bq >= 0 && bq < NN) { n0 = (int)a; n1 = (int)bq; }
    else { n0 = ((const int*)nbr)[0]; n1 = ((const int*)nbr)[1]; }
}
__device__ __forceinline__ int cam_of_w(int w, int ci, int n0, int n1) {
    if (w < 2) return ci;
    return (w == 2 || w == 4) ? n0 : n1;
}

// ---- projection, f32 op-order mirrored to the JAX reference, no FMA contraction ----
__device__ __forceinline__ void project_pix(const float* __restrict__ Pm, const float* __restrict__ ik,
                                            float fx, float fy, float d,
                                            float& gx, float& gy, float& sx, float& sy)
{
    float q0 = __fadd_rn(__fadd_rn(__fmul_rn(ik[0], fx), __fmul_rn(ik[1], fy)), ik[2]);
    float q1 = __fadd_rn(__fadd_rn(__fmul_rn(ik[3], fx), __fmul_rn(ik[4], fy)), ik[5]);
    float q2 = __fadd_rn(__fadd_rn(__fmul_rn(ik[6], fx), __fmul_rn(ik[7], fy)), ik[8]);
    float a0 = __fmul_rn(q0, d), a1 = __fmul_rn(q1, d), a2 = __fmul_rn(q2, d);
    float p0 = __fadd_rn(__fadd_rn(__fadd_rn(__fmul_rn(Pm[0], a0), __fmul_rn(Pm[1], a1)), __fmul_rn(Pm[2], a2)), Pm[3]);
    float p1 = __fadd_rn(__fadd_rn(__fadd_rn(__fmul_rn(Pm[4], a0), __fmul_rn(Pm[5], a1)), __fmul_rn(Pm[6], a2)), Pm[7]);
    float p2 = __fadd_rn(__fadd_rn(__fadd_rn(__fmul_rn(Pm[8], a0), __fmul_rn(Pm[9], a1)), __fmul_rn(Pm[10], a2)), Pm[11]);
    float z  = __fadd_rn(p2, 1e-7f);
    float xx = __fdiv_rn(p0, z);
    float yy = __fdiv_rn(p1, z);
    gx = __fmul_rn(__fsub_rn(__fdiv_rn(xx, 639.0f), 0.5f), 2.0f);
    gy = __fmul_rn(__fsub_rn(__fdiv_rn(yy, 383.0f), 0.5f), 2.0f);
    sx = __fmul_rn(__fmul_rn(__fadd_rn(gx, 1.0f), 0.5f), 639.0f);
    sy = __fmul_rn(__fmul_rn(__fadd_rn(gy, 1.0f), 0.5f), 383.0f);
}

// 4 predicated 4B scattered loads; nearest mask from a corner texel.
__device__ __forceinline__ void sample_u10(const unsigned* __restrict__ pk,
                                           const float* Pm, const float* ik, float d, int px_i, int py_i,
                                           float& i0, float& i1, float& i2, float& wmv, bool& isnanv)
{
    float gx, gy, sx, sy;
    project_pix(Pm, ik, (float)px_i, (float)py_i, d, gx, gy, sx, sy);
    float x0f = floorf(sx), y0f = floorf(sy);
    float wx = __fsub_rn(sx, x0f), wy = __fsub_rn(sy, y0f);
    int x0 = (int)x0f, y0 = (int)y0f;
    int x1 = x0 + 1, y1 = y0 + 1;
    bool vx0 = (x0 >= 0) && (x0 < WW), vx1 = (x1 >= 0) && (x1 < WW);
    bool vy0 = (y0 >= 0) && (y0 < HH), vy1 = (y1 >= 0) && (y1 < HH);
    unsigned u00 = 0u, u01 = 0u, u10 = 0u, u11 = 0u;
    if (vy0 && vx0) u00 = pk[y0 * WW + x0];
    if (vy0 && vx1) u01 = pk[y0 * WW + x1];
    if (vy1 && vx0) u10 = pk[y1 * WW + x0];
    if (vy1 && vx1) u11 = pk[y1 * WW + x1];
    float w00 = (1.0f - wx) * (1.0f - wy);
    float w01 = wx * (1.0f - wy);
    float w10 = (1.0f - wx) * wy;
    float w11 = wx * wy;
    float r00,g00,b00,m00, r01,g01,b01,m01, r10,g10,b10,m10, r11,g11,b11,m11;
    decTex(u00, r00,g00,b00,m00); decTex(u01, r01,g01,b01,m01);
    decTex(u10, r10,g10,b10,m10); decTex(u11, r11,g11,b11,m11);
    float v0 = ((r00*w00 + r01*w01) + r10*w10) + r11*w11;
    float v1 = ((g00*w00 + g01*w01) + g10*w10) + g11*w11;
    float v2 = ((b00*w00 + b01*w01) + b10*w10) + b11*w11;
    isnanv = (v0 != v0);
    i0 = isnanv ? 2.0f : v0;
    i1 = (v1 != v1) ? 2.0f : v1;
    i2 = (v2 != v2) ? 2.0f : v2;
    bool invalid = (gx > 1.0f) || (gx < -1.0f) || (gy > 1.0f) || (gy < -1.0f);
    float xr = rintf(sx), yr = rintf(sy);
    int xi = (int)xr, yi = (int)yr;
    bool vm = (xi >= 0) && (xi < WW) && (yi >= 0) && (yi < HH) && !invalid;
    bool selx = (xi == x1), sely = (yi == y1);
    float msel = sely ? (selx ? m11 : m10) : (selx ? m01 : m00);
    wmv = vm ? msel : 0.0f;
}

// Setup matrices (1 block, parallel over the 12 (w,b) mats).
__global__ void vr_setup(const float* __restrict__ K, const float* __restrict__ invK,
                         const float* __restrict__ p2c, const float* __restrict__ c2n,
                         const float* __restrict__ rel, const void* __restrict__ camI,
                         const void* __restrict__ nbr, float* __restrict__ ws)
{
    int t = threadIdx.x;
    int ci, n0, n1;
    get_cams(camI, nbr, ci, n0, n1);
    if (t == 0) {
        int* cams = (int*)(ws + WS_CAM);
        cams[0] = ci; cams[1] = ci; cams[2] = n0; cams[3] = n1; cams[4] = n0; cams[5] = n1;
        cams[6] = ci;
    }
    if (t < BB) {
        const float* ik = invK + (size_t)(t * NN + ci) * 16;
        float* dst = ws + WS_INVK + t * 9;
        dst[0] = ik[0]; dst[1] = ik[1]; dst[2] = ik[2];
        dst[3] = ik[4]; dst[4] = ik[5]; dst[5] = ik[6];
        dst[6] = ik[8]; dst[7] = ik[9]; dst[8] = ik[10];
    }
    if (t < 12) {
        int w = t / BB, b = t % BB;
        int cam = cam_of_w(w, ci, n0, n1);
        const float* Km = K + (size_t)(b * NN + cam) * 16;
        const float* T;
        if (w == 0)      T = p2c + (size_t)(b * NN + ci) * 16;
        else if (w == 1) T = c2n + (size_t)(b * NN + ci) * 16;
        else {
            int f = (w >= 4) ? 1 : 0;
            int n = (w == 3 || w == 5) ? 1 : 0;
            T = rel + (size_t)((f * 2 + n) * BB + b) * 16;
        }
        float* Pd = ws + WS_P + t * 12;
        for (int i = 0; i < 3; i++)
            for (int j = 0; j < 4; j++) {
                float s = __fadd_rn(__fadd_rn(__fadd_rn(
                              __fmul_rn(Km[i * 4 + 0], T[0 * 4 + j]),
                              __fmul_rn(Km[i * 4 + 1], T[1 * 4 + j])),
                              __fmul_rn(Km[i * 4 + 2], T[2 * 4 + j])),
                              __fmul_rn(Km[i * 4 + 3], T[3 * 4 + j]));
                Pd[i * 4 + j] = s;
            }
    }
}

// Pack 12 src images into unorm10 texels, 4 px/thread, float4 in / uint4 out.
__global__ __launch_bounds__(256) void vr_pack(
    const float* __restrict__ prev, const float* __restrict__ nxt,
    const float* __restrict__ maskT, const void* __restrict__ camI,
    const void* __restrict__ nbr, float* __restrict__ ws)
{
    int ci, n0, n1;
    get_cams(camI, nbr, ci, n0, n1);
    int group = blockIdx.x / GPB;
    int p4 = (blockIdx.x % GPB) * 256 + threadIdx.x;   // < HWSZ/4
    int p = 4 * p4;
    int w = group / BB, b = group % BB;
    int cam = cam_of_w(w, ci, n0, n1);
    const float* simg  = ((w == 0 || w == 2 || w == 3) ? prev : nxt) + (size_t)(b * NN + cam) * 3 * HWSZ;
    const float* smask = maskT + (size_t)(b * NN + cam) * HWSZ;
    float4 R = *(const float4*)(simg + p);
    float4 G = *(const float4*)(simg + HWSZ + p);
    float4 Bl = *(const float4*)(simg + 2 * HWSZ + p);
    float4 M = *(const float4*)(smask + p);
    uint4 u;
    u.x = encTex(R.x, G.x, Bl.x, M.x);
    u.y = encTex(R.y, G.y, Bl.y, M.y);
    u.z = encTex(R.z, G.z, Bl.z, M.z);
    u.w = encTex(R.w, G.w, Bl.w, M.w);
    ((uint4*)(ws + PK_OFF))[(size_t)group * (HWSZ / 4) + p4] = u;
}

// Ref-side pack, 4 px/thread; per-block partial sums to distinct slots (no atomics).
__global__ __launch_bounds__(256) void vr_packref(
    const float* __restrict__ org, const float* __restrict__ maskT,
    const float* __restrict__ depthT, const void* __restrict__ camI,
    const void* __restrict__ nbr, float* __restrict__ ws)
{
    int ci, n0, n1;
    get_cams(camI, nbr, ci, n0, n1);
    int b = blockIdx.x / GPB;
    int p4 = (blockIdx.x % GPB) * 256 + threadIdx.x;
    int p = 4 * p4;
    const float* rimg = org + (size_t)(b * NN + ci) * 3 * HWSZ;
    float4 R0 = *(const float4*)(rimg + p);
    float4 R1 = *(const float4*)(rimg + HWSZ + p);
    float4 R2 = *(const float4*)(rimg + 2 * HWSZ + p);
    float4 RM = *(const float4*)(maskT + (size_t)(b * NN + ci) * HWSZ + p);
    float4 DD = *(const float4*)(depthT + (size_t)(b * NN + ci) * HWSZ + p);
    float a0[4] = {R0.x, R0.y, R0.z, R0.w};
    float a1[4] = {R1.x, R1.y, R1.z, R1.w};
    float a2[4] = {R2.x, R2.y, R2.z, R2.w};
    float am[4] = {RM.x, RM.y, RM.z, RM.w};
    float ad[4] = {DD.x, DD.y, DD.z, DD.w};
    float4* rpk = (float4*)(ws + RP_OFF) + (size_t)b * HWSZ;
    float s = 0.f, q = 0.f;
#pragma unroll
    for (int k = 0; k < 4; k++) {
        float rs3 = a0[k] + a1[k] + a2[k];
        float rsq = a0[k] * a0[k] + a1[k] * a1[k] + a2[k] * a2[k];
        float4 v; v.x = rs3; v.y = ad[k]; v.z = am[k]; v.w = 0.0f;
        rpk[p + k] = v;
        s += rs3; q += rsq;
    }
    __shared__ float sred[4][2];
    int lane = threadIdx.x & 63, wv = threadIdx.x >> 6;
    for (int off = 32; off; off >>= 1) { s += __shfl_down(s, off); q += __shfl_down(q, off); }
    if (lane == 0) { sred[wv][0] = s; sred[wv][1] = q; }
    __syncthreads();
    if (threadIdx.x == 0) {
        float2 pq;
        pq.x = sred[0][0] + sred[1][0] + sred[2][0] + sred[3][0];
        pq.y = sred[0][1] + sred[1][1] + sred[2][1] + sred[3][1];
        ((float2*)(ws + PART_OFF))[blockIdx.x] = pq;
    }
}

__global__ __launch_bounds__(256) void vr_phaseA(float* __restrict__ ws)
{
    int group = blockIdx.x % 12;        // round-robin: all groups progress together
    int blkin = blockIdx.x / 12;
    int b = group % BB;
    float Pl[12], ikl[9];
    {
        const float* Pm = ws + WS_P + group * 12;
        const float* ik = ws + WS_INVK + b * 9;
#pragma unroll
        for (int i = 0; i < 12; i++) Pl[i] = Pm[i];
#pragma unroll
        for (int i = 0; i < 9; i++) ikl[i] = ik[i];
    }
    const float4* rpk = (const float4*)(ws + RP_OFF) + (size_t)b * HWSZ;
    const unsigned* pk = (const unsigned*)(ws + PK_OFF) + (size_t)group * HWSZ;
    unsigned* cache = (unsigned*)(ws + CACHE_OFF) + (size_t)group * HWSZ;

    float acc[5] = {0, 0, 0, 0, 0};
    for (int p = blkin * 256 + threadIdx.x; p < HWSZ; p += BPG * 256) {
        int py_i = p / WW, px_i = p - py_i * WW;
        float4 rp = rpk[p];
        float rs3 = rp.x, d = rp.y, rm = rp.z;
        float i0, i1, i2, wmv; bool isnanv;
        sample_u10(pk, Pl, ikl, d, px_i, py_i, i0, i1, i2, wmv, isnanv);
        cache[p] = isnanv ? (2u << 30) : encTex(i0, i1, i2, wmv);
        float m = (rm * wmv > 0.0f) ? 1.0f : 0.0f;
        float ws3 = i0 + i1 + i2;
        acc[0] += m;
        acc[1] += rs3 * m;
        acc[2] += ws3 * m;
        acc[3] += ws3;
        acc[4] += i0 * i0 + i1 * i1 + i2 * i2;
    }
    __shared__ float sred[4][5];
    int lane = threadIdx.x & 63, wv = threadIdx.x >> 6;
#pragma unroll
    for (int k = 0; k < 5; k++) {
        float v2 = acc[k];
        for (int off = 32; off; off >>= 1) v2 += __shfl_down(v2, off);
        if (lane == 0) sred[wv][k] = v2;
    }
    __syncthreads();
    if (threadIdx.x < 5) {
        float s = sred[0][threadIdx.x] + sred[1][threadIdx.x] + sred[2][threadIdx.x] + sred[3][threadIdx.x];
        atomicAdd(&ws[WS_ACC + group * 8 + threadIdx.x], s);
    }
}

__global__ void vr_finalize(float* __restrict__ ws)
{
    int t = threadIdx.x;   // 64 threads = 1 wave
    __shared__ float red[BB][2];
    const float2* part = (const float2*)(ws + PART_OFF);
    for (int b = 0; b < BB; b++) {
        float s = 0.f, q = 0.f;
        for (int i = t; i < GPB; i += 64) {
            float2 pq = part[b * GPB + i];
            s += pq.x; q += pq.y;
        }
        for (int off = 32; off; off >>= 1) { s += __shfl_down(s, off); q += __shfl_down(q, off); }
        if (t == 0) { red[b][0] = s; red[b][1] = q; }
    }
    __syncthreads();
    if (t >= 12) return;
    int w = t / BB;
    int wb = t % BB;
    const float* ac = ws + WS_ACC + t * 8;
    double cnt  = ac[0], smsk = ac[1], wmsk = ac[2];
    double wsum = ac[3], wsq  = ac[4];
    double ssum = red[wb][0];
    double ssq  = red[wb][1];
    double msum = 3.0 * cnt;
    double NT = 3.0 * (double)HWSZ;
    double smean = smsk / (msum + 1e-8);
    double svar  = (ssq - 2.0 * smean * ssum + NT * smean * smean) / NT;
    double sstd  = sqrt(svar + 1e-16);
    double wmean = wmsk / (msum + 1e-8);
    double wvar  = (wsq - 2.0 * wmean * wsum + NT * wmean * wmean) / NT;
    double wstd  = sqrt(wvar + 1e-16);
    float c0 = ws[WS_ACC + (w * BB + 0) * 8];
    float c1 = ws[WS_ACC + (w * BB + 1) * 8];
    float az = (c0 == 0.0f || c1 == 0.0f) ? 1.0f : 0.0f;
    float* st = ws + WS_STAT + t * 6;
    st[0] = (float)smean; st[1] = (float)sstd;
    st[2] = (float)wmean; st[3] = (float)wstd;
    st[4] = az;
}

__global__ __launch_bounds__(256) void vr_phaseB(const float* __restrict__ ws, float* __restrict__ out)
{
    int idx = blockIdx.x * 256 + threadIdx.x;
    int ob = idx / (BB * HWSZ);
    int rem = idx - ob * (BB * HWSZ);
    int b = rem / HWSZ;
    int p = rem - b * HWSZ;
    int w0 = (ob == 0) ? 0 : (ob == 1) ? 1 : (ob == 2) ? 2 : 4;
    int nw = (ob < 2) ? 1 : 2;
    float o0 = 0, o1 = 0, o2 = 0, om = 0;
    for (int k = 0; k < nw; k++) {
        int w = w0 + k;
        int group = w * BB + b;
        unsigned u = ((const unsigned*)(ws + CACHE_OFF))[(size_t)group * HWSZ + p];
        float i0, i1, i2, wmv;
        unsigned mb = u >> 30;
        if (mb == 2u) { i0 = i1 = i2 = 2.0f; wmv = 0.0f; }
        else decTex(u, i0, i1, i2, wmv);
        const float* st = ws + WS_STAT + group * 6;
        float smean = st[0], sstd = st[1], wmean = st[2], wstd = st[3];
        bool az = st[4] != 0.0f;
        float v0, v1, v2;
        if (az) { v0 = i0; v1 = i1; v2 = i2; }
        else {
            v0 = ((i0 - wmean) / (wstd + 1e-8f)) * sstd + smean; v0 *= wmv;
            v1 = ((i1 - wmean) / (wstd + 1e-8f)) * sstd + smean; v1 *= wmv;
            v2 = ((i2 - wmean) / (wstd + 1e-8f)) * sstd + smean; v2 *= wmv;
        }
        o0 += v0; o1 += v1; o2 += v2; om += wmv;
    }
    float* base = out + ((size_t)b * 16 + ob * 4) * HWSZ;
    base[p] = o0;
    base[HWSZ + p] = o1;
    base[2 * HWSZ + p] = o2;
    base[3 * HWSZ + p] = om;
}

extern "C" void kernel_launch(void* const* d_in, const int* in_sizes, int n_in,
                              void* d_out, int out_size, void* d_ws, size_t ws_size,
                              hipStream_t stream)
{
    const float* prev  = (const float*)d_in[0];
    const float* org   = (const float*)d_in[1];
    const float* nxt   = (const float*)d_in[2];
    const float* maskT = (const float*)d_in[3];
    const float* K     = (const float*)d_in[4];
    const float* invK  = (const float*)d_in[5];
    const float* dep   = (const float*)d_in[6];
    const float* p2c   = (const float*)d_in[7];
    const float* c2n   = (const float*)d_in[8];
    const float* rel   = (const float*)d_in[9];
    const void*  camI  = d_in[10];
    const void*  nbr   = d_in[11];
    float* ws  = (float*)d_ws;
    float* out = (float*)d_out;

    // header zero (acc, stats). ws_size known >= 78 MB from R4/R5; need here ~31.5 MB.
    hipMemsetAsync(ws, 0, 2048, stream);
    hipLaunchKernelGGL(vr_setup, dim3(1), dim3(64), 0, stream, K, invK, p2c, c2n, rel, camI, nbr, ws);
    hipLaunchKernelGGL(vr_pack, dim3(12 * GPB), dim3(256), 0, stream, prev, nxt, maskT, camI, nbr, ws);
    hipLaunchKernelGGL(vr_packref, dim3(2 * GPB), dim3(256), 0, stream, org, maskT, dep, camI, nbr, ws);
    hipLaunchKernelGGL(vr_phaseA, dim3(12 * BPG), dim3(256), 0, stream, ws);
    hipLaunchKernelGGL(vr_finalize, dim3(1), dim3(64), 0, stream, ws);
    hipLaunchKernelGGL(vr_phaseB, dim3(4 * BB * HWSZ / 256), dim3(256), 0, stream, ws, out);
}

// Round 9
// 58.023 us; speedup vs baseline: 6.2857x; 1.1185x over previous
//
#include <hip/hip_runtime.h>
#include <math.h>

#define HH 384
#define WW 640
#define HWSZ (HH*WW)
#define BB 2
#define NN 6
#define BPG 256                 // blocks per group in phaseA
#define GPB 240                 // blocks per image in prep (HWSZ/1024)

// ws float-offset layout:
//  header: WS_P 0..143, WS_INVK 144..161, WS_CAM 176..182,
//          WS_ACC 192..287 (12 x 8, zeroed by prep setup-block), WS_STAT 320..391
//  CACHE_OFF: 12*HWSZ uint   (unorm10 RGB + 2b wm sample cache)  11.8 MB
//  RP_OFF   : 2*HWSZ float4  (rs3, depth, rmask, 0)               7.9 MB
//  PK_OFF   : 12*HWSZ uint2  (pair texels: u10(x), u10(x+1))     23.6 MB
//  PART_OFF : 480 float2 ref partial sums (no atomics)
#define WS_P      0
#define WS_INVK   144
#define WS_CAM    176
#define WS_ACC    192
#define WS_STAT   320
#define CACHE_OFF 512
#define RP_OFF    (CACHE_OFF + 12 * HWSZ)
#define PK_OFF    (RP_OFF + 8 * HWSZ)
#define PART_OFF  (PK_OFF + 24 * HWSZ)

__device__ __forceinline__ unsigned enc10(float c) {
    c = fminf(fmaxf(c, 0.0f), 1.0f);
    return (unsigned)rintf(c * 1023.0f);
}
__device__ __forceinline__ unsigned encTex(float r, float g, float b, float m) {
    unsigned mb = (unsigned)rintf(fminf(fmaxf(m, 0.0f), 1.0f) * 3.0f);
    return enc10(r) | (enc10(g) << 10) | (enc10(b) << 20) | (mb << 30);
}
__device__ __forceinline__ void decTex(unsigned u, float& r, float& g, float& b, float& m) {
    const float s = 1.0f / 1023.0f;
    r = (float)(u & 1023u) * s;
    g = (float)((u >> 10) & 1023u) * s;
    b = (float)((u >> 20) & 1023u) * s;
    m = (float)(u >> 30) * (1.0f / 3.0f);
}

__device__ __forceinline__ void get_cams(const void* camI, const void* nbr,
                                         int& ci, int& n0, int& n1) {
    ci = ((const int*)camI)[0];
    long long a = ((const long long*)nbr)[0];
    long long bq = ((const long long*)nbr)[1];
    if (a >= 0 && a < NN && bq >= 0 && bq < NN) { n0 = (int)a; n1 = (int)bq; }
    else { n0 = ((const int*)nbr)[0]; n1 = ((const int*)nbr)[1]; }
}
__device__ __forceinline__ int cam_of_w(int w, int ci, int n0, int n1) {
    if (w < 2) return ci;
    return (w == 2 || w == 4) ? n0 : n1;
}

// ---- projection, f32 op-order mirrored to the JAX reference, no FMA contraction ----
__device__ __forceinline__ void project_pix(const float* __restrict__ Pm, const float* __restrict__ ik,
                                            float fx, float fy, float d,
                                            float& gx, float& gy, float& sx, float& sy)
{
    float q0 = __fadd_rn(__fadd_rn(__fmul_rn(ik[0], fx), __fmul_rn(ik[1], fy)), ik[2]);
    float q1 = __fadd_rn(__fadd_rn(__fmul_rn(ik[3], fx), __fmul_rn(ik[4], fy)), ik[5]);
    float q2 = __fadd_rn(__fadd_rn(__fmul_rn(ik[6], fx), __fmul_rn(ik[7], fy)), ik[8]);
    float a0 = __fmul_rn(q0, d), a1 = __fmul_rn(q1, d), a2 = __fmul_rn(q2, d);
    float p0 = __fadd_rn(__fadd_rn(__fadd_rn(__fmul_rn(Pm[0], a0), __fmul_rn(Pm[1], a1)), __fmul_rn(Pm[2], a2)), Pm[3]);
    float p1 = __fadd_rn(__fadd_rn(__fadd_rn(__fmul_rn(Pm[4], a0), __fmul_rn(Pm[5], a1)), __fmul_rn(Pm[6], a2)), Pm[7]);
    float p2 = __fadd_rn(__fadd_rn(__fadd_rn(__fmul_rn(Pm[8], a0), __fmul_rn(Pm[9], a1)), __fmul_rn(Pm[10], a2)), Pm[11]);
    float z  = __fadd_rn(p2, 1e-7f);
    float xx = __fdiv_rn(p0, z);
    float yy = __fdiv_rn(p1, z);
    gx = __fmul_rn(__fsub_rn(__fdiv_rn(xx, 639.0f), 0.5f), 2.0f);
    gy = __fmul_rn(__fsub_rn(__fdiv_rn(yy, 383.0f), 0.5f), 2.0f);
    sx = __fmul_rn(__fmul_rn(__fadd_rn(gx, 1.0f), 0.5f), 639.0f);
    sy = __fmul_rn(__fmul_rn(__fadd_rn(gy, 1.0f), 0.5f), 383.0f);
}

// Pair-texel sampler: 2 predicated 8B scattered loads (one per bilinear row).
__device__ __forceinline__ void sample_u10(const uint2* __restrict__ pk2,
                                           const float* Pm, const float* ik, float d, int px_i, int py_i,
                                           float& i0, float& i1, float& i2, float& wmv, bool& isnanv)
{
    float gx, gy, sx, sy;
    project_pix(Pm, ik, (float)px_i, (float)py_i, d, gx, gy, sx, sy);
    float x0f = floorf(sx), y0f = floorf(sy);
    float wx = __fsub_rn(sx, x0f), wy = __fsub_rn(sy, y0f);
    int x0 = (int)x0f, y0 = (int)y0f;
    int x1 = x0 + 1, y1 = y0 + 1;
    bool vx0 = (x0 >= 0) && (x0 < WW), vx1 = (x1 >= 0) && (x1 < WW);
    bool vy0 = (y0 >= 0) && (y0 < HH), vy1 = (y1 >= 0) && (y1 < HH);
    uint2 ra = {0u, 0u}, rb = {0u, 0u};
    if (vy0) {
        if (vx0) ra = pk2[y0 * WW + x0];
        else if (vx1) ra.y = ((const unsigned*)(pk2 + y0 * WW))[0];   // x0 == -1
    }
    if (vy1) {
        if (vx0) rb = pk2[y1 * WW + x0];
        else if (vx1) rb.y = ((const unsigned*)(pk2 + y1 * WW))[0];
    }
    // zero hi word when x1 OOB (pair spills into next row otherwise)
    if (!vx1) { ra.y = 0u; rb.y = 0u; }
    if (!vx0) { ra.x = 0u; rb.x = 0u; }
    float w00 = (1.0f - wx) * (1.0f - wy);
    float w01 = wx * (1.0f - wy);
    float w10 = (1.0f - wx) * wy;
    float w11 = wx * wy;
    float r00,g00,b00,m00, r01,g01,b01,m01, r10,g10,b10,m10, r11,g11,b11,m11;
    decTex(ra.x, r00,g00,b00,m00); decTex(ra.y, r01,g01,b01,m01);
    decTex(rb.x, r10,g10,b10,m10); decTex(rb.y, r11,g11,b11,m11);
    float v0 = ((r00*w00 + r01*w01) + r10*w10) + r11*w11;
    float v1 = ((g00*w00 + g01*w01) + g10*w10) + g11*w11;
    float v2 = ((b00*w00 + b01*w01) + b10*w10) + b11*w11;
    isnanv = (v0 != v0);
    i0 = isnanv ? 2.0f : v0;
    i1 = (v1 != v1) ? 2.0f : v1;
    i2 = (v2 != v2) ? 2.0f : v2;
    bool invalid = (gx > 1.0f) || (gx < -1.0f) || (gy > 1.0f) || (gy < -1.0f);
    float xr = rintf(sx), yr = rintf(sy);
    int xi = (int)xr, yi = (int)yr;
    bool vm = (xi >= 0) && (xi < WW) && (yi >= 0) && (yi < HH) && !invalid;
    bool selx = (xi == x1), sely = (yi == y1);
    float msel = sely ? (selx ? m11 : m10) : (selx ? m01 : m00);
    wmv = vm ? msel : 0.0f;
}

// Merged prep (no atomics, no fences): blocks [0,12*GPB) pack pair texels;
// [12*GPB, 14*GPB) pack ref-side + per-block partial sums; last block = setup.
__global__ __launch_bounds__(256) void vr_prep(
    const float* __restrict__ prev, const float* __restrict__ nxt,
    const float* __restrict__ org, const float* __restrict__ maskT,
    const float* __restrict__ depthT,
    const float* __restrict__ K, const float* __restrict__ invK,
    const float* __restrict__ p2c, const float* __restrict__ c2n,
    const float* __restrict__ rel, const void* __restrict__ camI,
    const void* __restrict__ nbr, float* __restrict__ ws)
{
    int ci, n0, n1;
    get_cams(camI, nbr, ci, n0, n1);
    int blk = blockIdx.x;
    if (blk < 12 * GPB) {
        int group = blk / GPB;
        int p4 = (blk % GPB) * 256 + threadIdx.x;
        int p = 4 * p4;
        int w = group / BB, b = group % BB;
        int cam = cam_of_w(w, ci, n0, n1);
        const float* simg  = ((w == 0 || w == 2 || w == 3) ? prev : nxt) + (size_t)(b * NN + cam) * 3 * HWSZ;
        const float* smask = maskT + (size_t)(b * NN + cam) * HWSZ;
        float4 R  = *(const float4*)(simg + p);
        float4 G  = *(const float4*)(simg + HWSZ + p);
        float4 Bl = *(const float4*)(simg + 2 * HWSZ + p);
        float4 M  = *(const float4*)(smask + p);
        int pn = (p + 4 < HWSZ) ? (p + 4) : (HWSZ - 1);
        float r4 = simg[pn], g4 = simg[HWSZ + pn], b4 = simg[2 * HWSZ + pn], m4 = smask[pn];
        unsigned t0 = encTex(R.x, G.x, Bl.x, M.x);
        unsigned t1 = encTex(R.y, G.y, Bl.y, M.y);
        unsigned t2 = encTex(R.z, G.z, Bl.z, M.z);
        unsigned t3 = encTex(R.w, G.w, Bl.w, M.w);
        unsigned t4 = encTex(r4, g4, b4, m4);
        uint4* dst = (uint4*)((uint2*)(ws + PK_OFF) + (size_t)group * HWSZ + p);
        uint4 lo; lo.x = t0; lo.y = t1; lo.z = t1; lo.w = t2;
        uint4 hi; hi.x = t2; hi.y = t3; hi.z = t3; hi.w = t4;
        dst[0] = lo;
        dst[1] = hi;
    } else if (blk < 14 * GPB) {
        int rblk = blk - 12 * GPB;
        int b = rblk / GPB;
        int p4 = (rblk % GPB) * 256 + threadIdx.x;
        int p = 4 * p4;
        const float* rimg = org + (size_t)(b * NN + ci) * 3 * HWSZ;
        float4 R0 = *(const float4*)(rimg + p);
        float4 R1 = *(const float4*)(rimg + HWSZ + p);
        float4 R2 = *(const float4*)(rimg + 2 * HWSZ + p);
        float4 RM = *(const float4*)(maskT + (size_t)(b * NN + ci) * HWSZ + p);
        float4 DD = *(const float4*)(depthT + (size_t)(b * NN + ci) * HWSZ + p);
        float a0[4] = {R0.x, R0.y, R0.z, R0.w};
        float a1[4] = {R1.x, R1.y, R1.z, R1.w};
        float a2[4] = {R2.x, R2.y, R2.z, R2.w};
        float am[4] = {RM.x, RM.y, RM.z, RM.w};
        float ad[4] = {DD.x, DD.y, DD.z, DD.w};
        float4* rpk = (float4*)(ws + RP_OFF) + (size_t)b * HWSZ;
        float s = 0.f, q = 0.f;
#pragma unroll
        for (int k = 0; k < 4; k++) {
            float rs3 = a0[k] + a1[k] + a2[k];
            float rsq = a0[k] * a0[k] + a1[k] * a1[k] + a2[k] * a2[k];
            float4 v; v.x = rs3; v.y = ad[k]; v.z = am[k]; v.w = 0.0f;
            rpk[p + k] = v;
            s += rs3; q += rsq;
        }
        __shared__ float sred[4][2];
        int lane = threadIdx.x & 63, wv = threadIdx.x >> 6;
        for (int off = 32; off; off >>= 1) { s += __shfl_down(s, off); q += __shfl_down(q, off); }
        if (lane == 0) { sred[wv][0] = s; sred[wv][1] = q; }
        __syncthreads();
        if (threadIdx.x == 0) {
            float2 pq;
            pq.x = sred[0][0] + sred[1][0] + sred[2][0] + sred[3][0];
            pq.y = sred[0][1] + sred[1][1] + sred[2][1] + sred[3][1];
            ((float2*)(ws + PART_OFF))[rblk] = pq;
        }
    } else {
        int t = threadIdx.x;
        if (t < 96) ws[WS_ACC + t] = 0.0f;        // re-zero accumulators each call
        if (t == 0) {
            int* cams = (int*)(ws + WS_CAM);
            cams[0] = ci; cams[1] = ci; cams[2] = n0; cams[3] = n1; cams[4] = n0; cams[5] = n1;
            cams[6] = ci;
        }
        if (t < BB) {
            const float* ik = invK + (size_t)(t * NN + ci) * 16;
            float* dst = ws + WS_INVK + t * 9;
            dst[0] = ik[0]; dst[1] = ik[1]; dst[2] = ik[2];
            dst[3] = ik[4]; dst[4] = ik[5]; dst[5] = ik[6];
            dst[6] = ik[8]; dst[7] = ik[9]; dst[8] = ik[10];
        }
        if (t < 12) {
            int w = t / BB, b = t % BB;
            int cam = cam_of_w(w, ci, n0, n1);
            const float* Km = K + (size_t)(b * NN + cam) * 16;
            const float* T;
            if (w == 0)      T = p2c + (size_t)(b * NN + ci) * 16;
            else if (w == 1) T = c2n + (size_t)(b * NN + ci) * 16;
            else {
                int f = (w >= 4) ? 1 : 0;
                int n = (w == 3 || w == 5) ? 1 : 0;
                T = rel + (size_t)((f * 2 + n) * BB + b) * 16;
            }
            float* Pd = ws + WS_P + t * 12;
            for (int i = 0; i < 3; i++)
                for (int j = 0; j < 4; j++) {
                    float s = __fadd_rn(__fadd_rn(__fadd_rn(
                                  __fmul_rn(Km[i * 4 + 0], T[0 * 4 + j]),
                                  __fmul_rn(Km[i * 4 + 1], T[1 * 4 + j])),
                                  __fmul_rn(Km[i * 4 + 2], T[2 * 4 + j])),
                                  __fmul_rn(Km[i * 4 + 3], T[3 * 4 + j]));
                    Pd[i * 4 + j] = s;
                }
        }
    }
}

__global__ __launch_bounds__(256) void vr_phaseA(float* __restrict__ ws)
{
    int group = blockIdx.x % 12;        // round-robin: all groups progress together
    int blkin = blockIdx.x / 12;
    int b = group % BB;
    float Pl[12], ikl[9];
    {
        const float* Pm = ws + WS_P + group * 12;
        const float* ik = ws + WS_INVK + b * 9;
#pragma unroll
        for (int i = 0; i < 12; i++) Pl[i] = Pm[i];
#pragma unroll
        for (int i = 0; i < 9; i++) ikl[i] = ik[i];
    }
    const float4* rpk = (const float4*)(ws + RP_OFF) + (size_t)b * HWSZ;
    const uint2* pk2 = (const uint2*)(ws + PK_OFF) + (size_t)group * HWSZ;
    unsigned* cache = (unsigned*)(ws + CACHE_OFF) + (size_t)group * HWSZ;

    float acc[5] = {0, 0, 0, 0, 0};
    for (int p = blkin * 256 + threadIdx.x; p < HWSZ; p += BPG * 256) {
        int py_i = p / WW, px_i = p - py_i * WW;
        float4 rp = rpk[p];
        float rs3 = rp.x, d = rp.y, rm = rp.z;
        float i0, i1, i2, wmv; bool isnanv;
        sample_u10(pk2, Pl, ikl, d, px_i, py_i, i0, i1, i2, wmv, isnanv);
        cache[p] = isnanv ? (2u << 30) : encTex(i0, i1, i2, wmv);
        float m = (rm * wmv > 0.0f) ? 1.0f : 0.0f;
        float ws3 = i0 + i1 + i2;
        acc[0] += m;
        acc[1] += rs3 * m;
        acc[2] += ws3 * m;
        acc[3] += ws3;
        acc[4] += i0 * i0 + i1 * i1 + i2 * i2;
    }
    __shared__ float sred[4][5];
    int lane = threadIdx.x & 63, wv = threadIdx.x >> 6;
#pragma unroll
    for (int k = 0; k < 5; k++) {
        float v2 = acc[k];
        for (int off = 32; off; off >>= 1) v2 += __shfl_down(v2, off);
        if (lane == 0) sred[wv][k] = v2;
    }
    __syncthreads();
    if (threadIdx.x < 5) {
        float s = sred[0][threadIdx.x] + sred[1][threadIdx.x] + sred[2][threadIdx.x] + sred[3][threadIdx.x];
        atomicAdd(&ws[WS_ACC + group * 8 + threadIdx.x], s);
    }
}

__global__ void vr_finalize(float* __restrict__ ws)
{
    int t = threadIdx.x;   // 64 threads = 1 wave
    __shared__ float red[BB][2];
    const float2* part = (const float2*)(ws + PART_OFF);
    for (int b = 0; b < BB; b++) {
        float s = 0.f, q = 0.f;
        for (int i = t; i < GPB; i += 64) {
            float2 pq = part[b * GPB + i];
            s += pq.x; q += pq.y;
        }
        for (int off = 32; off; off >>= 1) { s += __shfl_down(s, off); q += __shfl_down(q, off); }
        if (t == 0) { red[b][0] = s; red[b][1] = q; }
    }
    __syncthreads();
    if (t >= 12) return;
    int w = t / BB;
    int wb = t % BB;
    const float* ac = ws + WS_ACC + t * 8;
    double cnt  = ac[0], smsk = ac[1], wmsk = ac[2];
    double wsum = ac[3], wsq  = ac[4];
    double ssum = red[wb][0];
    double ssq  = red[wb][1];
    double msum = 3.0 * cnt;
    double NT = 3.0 * (double)HWSZ;
    double smean = smsk / (msum + 1e-8);
    double svar  = (ssq - 2.0 * smean * ssum + NT * smean * smean) / NT;
    double sstd  = sqrt(svar + 1e-16);
    double wmean = wmsk / (msum + 1e-8);
    double wvar  = (wsq - 2.0 * wmean * wsum + NT * wmean * wmean) / NT;
    double wstd  = sqrt(wvar + 1e-16);
    float c0 = ws[WS_ACC + (w * BB + 0) * 8];
    float c1 = ws[WS_ACC + (w * BB + 1) * 8];
    float az = (c0 == 0.0f || c1 == 0.0f) ? 1.0f : 0.0f;
    float* st = ws + WS_STAT + t * 6;
    st[0] = (float)smean; st[1] = (float)sstd;
    st[2] = (float)wmean; st[3] = (float)wstd;
    st[4] = az;
}

__global__ __launch_bounds__(256) void vr_phaseB(const float* __restrict__ ws, float* __restrict__ out)
{
    int idx = blockIdx.x * 256 + threadIdx.x;
    int ob = idx / (BB * HWSZ);
    int rem = idx - ob * (BB * HWSZ);
    int b = rem / HWSZ;
    int p = rem - b * HWSZ;
    int w0 = (ob == 0) ? 0 : (ob == 1) ? 1 : (ob == 2) ? 2 : 4;
    int nw = (ob < 2) ? 1 : 2;
    float o0 = 0, o1 = 0, o2 = 0, om = 0;
    for (int k = 0; k < nw; k++) {
        int w = w0 + k;
        int group = w * BB + b;
        unsigned u = ((const unsigned*)(ws + CACHE_OFF))[(size_t)group * HWSZ + p];
        float i0, i1, i2, wmv;
        unsigned mb = u >> 30;
        if (mb == 2u) { i0 = i1 = i2 = 2.0f; wmv = 0.0f; }
        else decTex(u, i0, i1, i2, wmv);
        const float* st = ws + WS_STAT + group * 6;
        float smean = st[0], sstd = st[1], wmean = st[2], wstd = st[3];
        bool az = st[4] != 0.0f;
        float v0, v1, v2;
        if (az) { v0 = i0; v1 = i1; v2 = i2; }
        else {
            v0 = ((i0 - wmean) / (wstd + 1e-8f)) * sstd + smean; v0 *= wmv;
            v1 = ((i1 - wmean) / (wstd + 1e-8f)) * sstd + smean; v1 *= wmv;
            v2 = ((i2 - wmean) / (wstd + 1e-8f)) * sstd + smean; v2 *= wmv;
        }
        o0 += v0; o1 += v1; o2 += v2; om += wmv;
    }
    float* base = out + ((size_t)b * 16 + ob * 4) * HWSZ;
    base[p] = o0;
    base[HWSZ + p] = o1;
    base[2 * HWSZ + p] = o2;
    base[3 * HWSZ + p] = om;
}

extern "C" void kernel_launch(void* const* d_in, const int* in_sizes, int n_in,
                              void* d_out, int out_size, void* d_ws, size_t ws_size,
                              hipStream_t stream)
{
    const float* prev  = (const float*)d_in[0];
    const float* org   = (const float*)d_in[1];
    const float* nxt   = (const float*)d_in[2];
    const float* maskT = (const float*)d_in[3];
    const float* K     = (const float*)d_in[4];
    const float* invK  = (const float*)d_in[5];
    const float* dep   = (const float*)d_in[6];
    const float* p2c   = (const float*)d_in[7];
    const float* c2n   = (const float*)d_in[8];
    const float* rel   = (const float*)d_in[9];
    const void*  camI  = d_in[10];
    const void*  nbr   = d_in[11];
    float* ws  = (float*)d_ws;
    float* out = (float*)d_out;

    // ws need ~43.3 MB; ws_size known >= 78 MB from R4/R5 runs.
    hipLaunchKernelGGL(vr_prep, dim3(14 * GPB + 1), dim3(256), 0, stream,
                       prev, nxt, org, maskT, dep, K, invK, p2c, c2n, rel, camI, nbr, ws);
    hipLaunchKernelGGL(vr_phaseA, dim3(12 * BPG), dim3(256), 0, stream, ws);
    hipLaunchKernelGGL(vr_finalize, dim3(1), dim3(64), 0, stream, ws);
    hipLaunchKernelGGL(vr_phaseB, dim3(4 * BB * HWSZ / 256), dim3(256), 0, stream, ws, out);
}